// Round 8
// baseline (330.742 us; speedup 1.0000x reference)
//
#include <hip/hip_runtime.h>

// ---------------------------------------------------------------------------
// Types & helpers
// ---------------------------------------------------------------------------
typedef __attribute__((ext_vector_type(8))) short bf16x8;
typedef __attribute__((ext_vector_type(4))) float f32x4;

__device__ __forceinline__ short f2bf(float f) {
  union { float f; unsigned u; } a; a.f = f;
  unsigned r = a.u + 0x7fffu + ((a.u >> 16) & 1u);   // RNE
  return (short)(r >> 16);
}
__device__ __forceinline__ float bf2f(short s) {
  union { unsigned u; float f; } a;
  a.u = ((unsigned)(unsigned short)s) << 16; return a.f;
}
__device__ __forceinline__ float blo(unsigned u) { union { unsigned u; float f; } a; a.u = u << 16; return a.f; }
__device__ __forceinline__ float bhi(unsigned u) { union { unsigned u; float f; } a; a.u = u & 0xffff0000u; return a.f; }
__device__ __forceinline__ unsigned packbf(float lo, float hi) {
  return (unsigned)(unsigned short)f2bf(lo) | ((unsigned)(unsigned short)f2bf(hi) << 16);
}
__device__ __forceinline__ void ldscp16(const void* g, void* l) {
  __builtin_amdgcn_global_load_lds((const __attribute__((address_space(1))) void*)g,
                                   (__attribute__((address_space(3))) void*)l, 16, 0, 0);
}
__device__ __forceinline__ void stv(float* p, float v) { *p = v; }
__device__ __forceinline__ void stv(short* p, float v) { *p = f2bf(v); }

// ---------------------------------------------------------------------------
// Merged setup (unchanged).
// ---------------------------------------------------------------------------
__global__ __launch_bounds__(256) void setup_all(
    const float* __restrict__ w0, const float* __restrict__ w1,
    const float* __restrict__ w2, const float* __restrict__ w3,
    const float* __restrict__ w4, const float* __restrict__ w5,
    const float* __restrict__ w6, const float* __restrict__ w7,
    const float* __restrict__ g_s, const float* __restrict__ g_t,
    short* __restrict__ Wb, float* __restrict__ zs,
    const float* __restrict__ qs_b, const float* __restrict__ vs_b,
    const float* __restrict__ ps_b, const float* __restrict__ qt_b,
    const float* __restrict__ vt_b, const float* __restrict__ pt_b,
    float* __restrict__ bt_s, float* __restrict__ bt_t,
    float* __restrict__ wus, float* __restrict__ wut) {
  const int bid = blockIdx.x, tid = threadIdx.x;
  if (bid < 8192) {                                  // ---- cvt_w ----
    int idx = bid * 256 + tid;
    const float* ws[8] = {w0, w1, w2, w3, w4, w5, w6, w7};
    int wi = idx >> 18, loc = idx & 262143;
    int r = loc >> 9, q = loc & 511;
    float v, g;
    if (wi == 3 || wi == 7) { v = ws[wi][loc]; g = 1.f; }
    else {                                           // transposed, gamma on c_in=r
      v = ws[wi][q * 512 + r];
      g = (wi <= 2) ? g_s[r] : g_t[r];
    }
    Wb[idx] = f2bf(v * g);
  } else if (bid < 8512) {                           // ---- zero 320 KB ----
    zs[(bid - 8192) * 256 + tid] = 0.f;
  } else {                                           // ---- row folds ----
    const int w = tid >> 6, lane = tid & 63;
    const int b = (bid - 8512) * 4 + w;              // [0,2048)
    float s = 0.f;
    if (b < 1024) {                                  // bt = p_w.v_b + p_b
      const bool sp = b < 512;
      const float* W = sp ? w3 : w7;                 // ps_w : pt_w
      const float* vb = sp ? vs_b : vt_b;
      const int r = b & 511;
#pragma unroll
      for (int c = lane; c < 512; c += 64) s += W[r * 512 + c] * vb[c];
#pragma unroll
      for (int off = 32; off > 0; off >>= 1) s += __shfl_xor(s, off);
      if (lane == 0) (sp ? bt_s : bt_t)[r] = s + (sp ? ps_b : pt_b)[r];
    } else {                                         // wu = g * K_w^T.q_b
      const bool sp = b < 1536;
      const float* W = sp ? w1 : w5;                 // ks_w : kt_w
      const float* qb = sp ? qs_b : qt_b;
      const int c = b & 511;
#pragma unroll
      for (int o = lane; o < 512; o += 64) s += W[o * 512 + c] * qb[o];
#pragma unroll
      for (int off = 32; off > 0; off >>= 1) s += __shfl_xor(s, off);
      if (lane == 0)
        (sp ? wus : wut)[c] = s * (sp ? g_s[c] : g_t[c]);
    }
  }
}

// ---------------------------------------------------------------------------
// Transpose + sum-of-squares + u-dot (unchanged).
// ---------------------------------------------------------------------------
__global__ __launch_bounds__(256) void txp_sumsq(
    const float* __restrict__ src, short* __restrict__ dst,
    short* __restrict__ xb, float* __restrict__ ss,
    const float* __restrict__ wu, float* __restrict__ us) {
  constexpr long N = 16384;
  __shared__ short T[64][66];
  __shared__ float part[16][16][4];
  __shared__ float part2[16][16][4];
  const int tid = threadIdx.x;
  const long n0 = (long)blockIdx.x * 64;
  const int c0 = blockIdx.y * 64;
  const int n4 = (tid & 15) * 4;
  float s0 = 0.f, s1 = 0.f, s2 = 0.f, s3 = 0.f;
  float u0 = 0.f, u1 = 0.f, u2 = 0.f, u3 = 0.f;
#pragma unroll
  for (int i = 0; i < 4; ++i) {
    int cl = i * 16 + (tid >> 4);
    float4 v = *(const float4*)&src[(long)(c0 + cl) * N + n0 + n4];
    float wc = wu[c0 + cl];
    s0 += v.x * v.x; s1 += v.y * v.y; s2 += v.z * v.z; s3 += v.w * v.w;
    u0 += wc * v.x; u1 += wc * v.y; u2 += wc * v.z; u3 += wc * v.w;
    short e0 = f2bf(v.x), e1 = f2bf(v.y), e2 = f2bf(v.z), e3 = f2bf(v.w);
    T[n4 + 0][cl] = e0; T[n4 + 1][cl] = e1;
    T[n4 + 2][cl] = e2; T[n4 + 3][cl] = e3;
    uint2 o;
    o.x = (unsigned)(unsigned short)e0 | ((unsigned)(unsigned short)e1 << 16);
    o.y = (unsigned)(unsigned short)e2 | ((unsigned)(unsigned short)e3 << 16);
    *(uint2*)&xb[(long)(c0 + cl) * N + n0 + n4] = o;
  }
  part[tid >> 4][tid & 15][0] = s0; part[tid >> 4][tid & 15][1] = s1;
  part[tid >> 4][tid & 15][2] = s2; part[tid >> 4][tid & 15][3] = s3;
  part2[tid >> 4][tid & 15][0] = u0; part2[tid >> 4][tid & 15][1] = u1;
  part2[tid >> 4][tid & 15][2] = u2; part2[tid >> 4][tid & 15][3] = u3;
  __syncthreads();
  if (tid < 64) {
    float s = 0.f, u = 0.f;
#pragma unroll
    for (int cg = 0; cg < 16; ++cg) {
      s += part[cg][tid >> 2][tid & 3];
      u += part2[cg][tid >> 2][tid & 3];
    }
    atomicAdd(&ss[n0 + tid], s);
    atomicAdd(&us[n0 + tid], u);
  }
#pragma unroll
  for (int p = 0; p < 4; ++p) {
    int nl = p * 16 + (tid >> 4);
    int cl = (tid & 15) * 4;
    uint2 o;
    o.x = (unsigned)(unsigned short)T[nl][cl] |
          ((unsigned)(unsigned short)T[nl][cl + 1] << 16);
    o.y = (unsigned)(unsigned short)T[nl][cl + 2] |
          ((unsigned)(unsigned short)T[nl][cl + 3] << 16);
    *(uint2*)&dst[(n0 + nl) * 512 + c0 + cl] = o;
  }
}

// ---------------------------------------------------------------------------
// Old 2-barrier template — retained ONLY for the tiny weight-fold GEMM.
// ---------------------------------------------------------------------------
template <typename OutT, int BM = 128, int FOLD = 0, int BK = 64>
__global__ __launch_bounds__(256, 4) void gemm_nt(
    const short* __restrict__ A, const short* __restrict__ B,
    OutT* __restrict__ D, int K, int lda, int ldb, int ldd, float scale) {
  constexpr int WR = BM / 64;
  constexpr int WC = 4 / WR;
  constexpr int NW = (128 / WC) / 16;
  constexpr int CH = BK / 8;
  constexpr int MSK = CH - 1;
  constexpr int RPR = 256 / CH;
  __shared__ short As[BM * BK];
  __shared__ short Bs[128 * BK];
  const int tid = threadIdx.x;
  const int bz = blockIdx.z;
  const long i0 = (long)blockIdx.x * BM;
  const long j0 = (long)blockIdx.y * 128;
  long aOff, bOff;
  if (FOLD) {
    aOff = 262144L * (bz < 2 ? 3 + 4 * bz : 4 * (bz - 2));
    bOff = 262144L * (bz < 2 ? 2 + 4 * bz : 1 + 4 * (bz - 2));
  } else {
    aOff = 0; bOff = 0;
  }
  const short* Ab = A + aOff + i0 * lda;
  const short* Bb = B + bOff + j0 * ldb;
  const int srow = tid / CH, scol = tid & MSK;
  const int lane = tid & 63;
  const int waveid = tid >> 6;
  const int wr = (waveid / WC) * 64;
  const int wc = (waveid % WC) * 64;
  const int quad = lane >> 4, l15 = lane & 15;

  f32x4 acc[4][NW] = {};

  for (int k0 = 0; k0 < K; k0 += BK) {
    __syncthreads();
#pragma unroll
    for (int p = 0; p < BM / RPR; ++p) {
      int row = p * RPR + srow;
      int gc = (scol ^ (row & MSK)) << 3;
      ldscp16(Ab + (long)row * lda + k0 + gc, &As[p * 2048 + tid * 8]);
    }
#pragma unroll
    for (int p = 0; p < 128 / RPR; ++p) {
      int row = p * RPR + srow;
      int gc = (scol ^ (row & MSK)) << 3;
      ldscp16(Bb + (long)row * ldb + k0 + gc, &Bs[p * 2048 + tid * 8]);
    }
    __syncthreads();
#pragma unroll
    for (int kk = 0; kk < BK / 32; ++kk) {
      bf16x8 af[4], bfr[NW];
#pragma unroll
      for (int a = 0; a < 4; ++a) {
        int row = wr + a * 16 + l15;
        int g = kk * 4 + quad;
        af[a] = *(const bf16x8*)&As[row * BK + ((g ^ (row & MSK)) << 3)];
      }
#pragma unroll
      for (int b = 0; b < NW; ++b) {
        int row = wc + b * 16 + l15;
        int g = kk * 4 + quad;
        bfr[b] = *(const bf16x8*)&Bs[row * BK + ((g ^ (row & MSK)) << 3)];
      }
#pragma unroll
      for (int a = 0; a < 4; ++a)
#pragma unroll
        for (int b = 0; b < NW; ++b)
          acc[a][b] = __builtin_amdgcn_mfma_f32_16x16x32_bf16(af[a], bfr[b], acc[a][b], 0, 0, 0);
    }
  }

  const long Doff = (long)bz * 262144L;
#pragma unroll
  for (int a = 0; a < 4; ++a) {
    const int rb = (int)i0 + wr + a * 16 + quad * 4;
#pragma unroll
    for (int b = 0; b < NW; ++b) {
      const int cc = (int)j0 + wc + b * 16 + l15;
#pragma unroll
      for (int r = 0; r < 4; ++r)
        stv(D + Doff + (long)(rb + r) * ldd + cc, acc[a][b][r] * scale);
    }
  }
}

// ---------------------------------------------------------------------------
// gemm8 — 8-phase, triple-buffered, counted-vmcnt NT GEMM (T3+T4+T5).
// 512 threads = 8 waves; wave tile 64x64 (MR=NW=4); BK=64; BM x BN is
// 256x128 or 128x256 (wave grid (BM/64)x(BN/64)). LDS = 3 bufs x 48 KB
// = 144 KB (fits 160 KB/CU; 1 block/CU).
//
// Pipeline (depth 3): prologue stages tiles 0,1 (6 loads/thread each).
// Iter t: s_waitcnt vmcnt(6)  <- tile t resident, tile t+1's 6 loads stay
//         IN FLIGHT (never drain to 0 in the loop — T4, m218);
//         barrier; then 4 phases, each:
//           {6 ds_read_b128 frags} {2 gload_lds of tile t+2 -> buf (t+2)%3}
//           barrier; lgkmcnt(0); setprio(1); 8 MFMA; setprio(0); barrier
// (fine ds_read ∥ stage ∥ MFMA interleave per phase — the m196 lever; the
//  per-phase barriers create the wave role-split that makes setprio pay.)
// Buffer safety: stage writes (t+2)%3, reads are from t%3 — distinct; the
// buffer being overwritten held tile t-1, whose reads finished at t-1's
// last barrier. vmcnt accounting: at iter-t top the only newer loads are
// tile t+1's 6 -> vmcnt(6) exactly drains tile t.
// Epilogue modes as before: SCALE {0 none,1 row-rms,3 row-recip,4 QK-EXP},
// BIAS {0,1 row,2 col}, RESID {0,2 bf16 same-layout,3 bf16 transposed},
// EPI {0,1 exp-rowsum,3 sumsq+dot}.
// ---------------------------------------------------------------------------
template <typename OutT, int BIAS_MODE, int SCALE_MODE, int RESID_MODE, int EPI,
          int BM, int BN, int SWZ>
__global__ __launch_bounds__(512, 1) void gemm8(
    const short* __restrict__ A, const short* __restrict__ B,
    OutT* __restrict__ D, const float* __restrict__ bias,
    const float* __restrict__ ssv, const float* __restrict__ uvec,
    float* __restrict__ rs, float* __restrict__ rs2,
    const float* __restrict__ wvec, const short* __restrict__ residb,
    int K, int lda, int ldb, int ldd,
    long aBatch, long bBatch, long dBatch, long sBatch, float scale) {
  constexpr int WN = BN / 64;                        // wave cols (8 waves tot)
  constexpr int ACH = BM * 8;                        // A 16B-chunks per tile
  __shared__ short As[3][BM * 64];
  __shared__ short Bs[3][BN * 64];
  const int tid = threadIdx.x;
  const int lane = tid & 63, w = tid >> 6;
  const int quad = lane >> 4, l15 = lane & 15;

  int lin = blockIdx.x + gridDim.x * (blockIdx.y + gridDim.y * blockIdx.z);
  if (SWZ) {
    const int nwg = gridDim.x * gridDim.y * gridDim.z;
    const int q = nwg >> 3, r = nwg & 7;
    const int xcd = lin & 7, idx = lin >> 3;
    lin = (xcd < r ? xcd * (q + 1) : r * (q + 1) + (xcd - r) * q) + idx;
  }
  const int bx = lin % gridDim.x;
  const int t1 = lin / gridDim.x;
  const int by = t1 % gridDim.y;
  const int bz = t1 / gridDim.y;

  const long i0 = (long)bx * BM;
  const long j0 = (long)by * BN;
  const short* Ab = A + bz * aBatch + i0 * lda;
  const short* Bb = B + bz * bBatch + j0 * ldb;
  const int wr = (w / WN) * 64;
  const int wc = (w % WN) * 64;

  f32x4 acc[4][4] = {};

  // one staging slot: s in [0,6); A-chunks first, then B-chunks
  auto stage1 = [&](int buf, int k0, int s) {
    int idx = s * 512 + tid;
    if (idx < ACH) {
      int row = idx >> 3, c = idx & 7;
      ldscp16(Ab + (long)row * lda + k0 + ((c ^ (row & 7)) << 3),
              &As[buf][idx * 8]);
    } else {
      int j = idx - ACH;
      int row = j >> 3, c = j & 7;
      ldscp16(Bb + (long)row * ldb + k0 + ((c ^ (row & 7)) << 3),
              &Bs[buf][j * 8]);
    }
  };

  const int NT = K >> 6;
#pragma unroll
  for (int s = 0; s < 6; ++s) stage1(0, 0, s);
  if (NT > 1)
#pragma unroll
    for (int s = 0; s < 6; ++s) stage1(1, 64, s);

  for (int t = 0; t < NT; ++t) {
    const int buf = t % 3;
    if (t + 1 < NT) asm volatile("s_waitcnt vmcnt(6)" ::: "memory");
    else            asm volatile("s_waitcnt vmcnt(0)" ::: "memory");
    __builtin_amdgcn_s_barrier();                    // tile t resident everywhere
    const short* Ar = As[buf];
    const short* Br = Bs[buf];
    const bool pre = (t + 2 < NT);
    const int pbuf = (t + 2) % 3, pk = (t + 2) * 64;
#pragma unroll
    for (int p = 0; p < 4; ++p) {
      const int kk = p >> 1, bh = p & 1;
      bf16x8 af[4], bfr[2];
#pragma unroll
      for (int a = 0; a < 4; ++a) {
        int row = wr + a * 16 + l15;
        int g = kk * 4 + quad;
        af[a] = *(const bf16x8*)&Ar[row * 64 + ((g ^ (row & 7)) << 3)];
      }
#pragma unroll
      for (int b = 0; b < 2; ++b) {
        int row = wc + (bh * 2 + b) * 16 + l15;
        int g = kk * 4 + quad;
        bfr[b] = *(const bf16x8*)&Br[row * 64 + ((g ^ (row & 7)) << 3)];
      }
      if (pre && p < 3) { stage1(pbuf, pk, 2 * p); stage1(pbuf, pk, 2 * p + 1); }
      __builtin_amdgcn_s_barrier();
      asm volatile("s_waitcnt lgkmcnt(0)" ::: "memory");
      __builtin_amdgcn_s_setprio(1);
#pragma unroll
      for (int a = 0; a < 4; ++a) {
        acc[a][bh * 2 + 0] = __builtin_amdgcn_mfma_f32_16x16x32_bf16(
            af[a], bfr[0], acc[a][bh * 2 + 0], 0, 0, 0);
        acc[a][bh * 2 + 1] = __builtin_amdgcn_mfma_f32_16x16x32_bf16(
            af[a], bfr[1], acc[a][bh * 2 + 1], 0, 0, 0);
      }
      __builtin_amdgcn_s_setprio(0);
      __builtin_amdgcn_s_barrier();
    }
  }

  const long Doff = bz * dBatch;
#pragma unroll
  for (int a = 0; a < 4; ++a) {
    const int rb = (int)i0 + wr + a * 16 + quad * 4;   // C/D: row = quad*4+reg
    float rsc[4];
    if (SCALE_MODE == 1 || SCALE_MODE == 4) {
#pragma unroll
      for (int r = 0; r < 4; ++r)
        rsc[r] = 22.627416997969522f /
                 fmaxf(sqrtf(ssv[bz * sBatch + rb + r]), 1e-12f);
    }
    if (SCALE_MODE == 3) {
#pragma unroll
      for (int r = 0; r < 4; ++r)
        rsc[r] = 1.f / ssv[bz * sBatch + rb + r];
    }
    float rp1[4] = {0.f, 0.f, 0.f, 0.f};
    float rp2[4] = {0.f, 0.f, 0.f, 0.f};
#pragma unroll
    for (int b = 0; b < 4; ++b) {
      const int cc = (int)j0 + wc + b * 16 + l15;      // C/D: col = lane&15
      float csc = 1.f, uu = 0.f, wv = 0.f;
      if (SCALE_MODE == 4)
        csc = 22.627416997969522f /
              fmaxf(sqrtf(ssv[bz * sBatch + cc]), 1e-12f);
      if (SCALE_MODE == 4) uu = uvec[bz * sBatch + cc];
      if (EPI == 3) wv = wvec[cc];
      uint2 rtv;
      if (RESID_MODE == 3)
        rtv = *(const uint2*)&residb[(long)cc * 512 + rb];
#pragma unroll
      for (int r = 0; r < 4; ++r) {
        float val;
        if (SCALE_MODE == 4) {
          val = __expf(scale * csc * (rsc[r] * acc[a][b][r] + uu));
          rp1[r] += val;
          val *= csc;
        } else {
          val = acc[a][b][r] * scale;
          if (SCALE_MODE == 1 || SCALE_MODE == 3) val *= rsc[r];
        }
        if (BIAS_MODE == 1) val += bias[rb + r];
        if (BIAS_MODE == 2) val += bias[cc];
        const long off = Doff + (long)(rb + r) * ldd + cc;
        if (RESID_MODE == 2) val += bf2f(residb[off]);
        if (RESID_MODE == 3) val += bf2f(((const short*)&rtv)[r]);
        stv(D + off, val);
        if (EPI == 3) { rp1[r] += val * val; rp2[r] += val * wv; }
      }
    }
    if (EPI == 1 || EPI == 3) {
#pragma unroll
      for (int r = 0; r < 4; ++r) {
        float s = rp1[r];
#pragma unroll
        for (int off = 1; off < 16; off <<= 1) s += __shfl_xor(s, off);
        if (l15 == 0) atomicAdd(&rs[bz * sBatch + rb + r], s);
      }
      if (EPI == 3) {
#pragma unroll
        for (int r = 0; r < 4; ++r) {
          float s = rp2[r];
#pragma unroll
          for (int off = 1; off < 16; off <<= 1) s += __shfl_xor(s, off);
          if (l15 == 0) atomicAdd(&rs2[bz * sBatch + rb + r], s);
        }
      }
    }
  }
}

// ---------------------------------------------------------------------------
// Temporal attention v5 (unchanged).
// ---------------------------------------------------------------------------
__global__ __launch_bounds__(256) void temporal_attn_v5(
    const short* __restrict__ h2, const short* __restrict__ Tt,
    const float* __restrict__ ss, const float* __restrict__ ut,
    const int* __restrict__ wndp, short* __restrict__ o, float scale) {
  constexpr int RS = 520;                            // 512 + 8 pad
  __shared__ short hq[16 * RS];
  __shared__ short tk[16 * RS];
  __shared__ float Plds[16][17];
  const int tid = threadIdx.x;
  const int w = tid >> 6, lane = tid & 63;
  const int hw = blockIdx.x;
  const int wnd = *wndp;

#pragma unroll
  for (int i = 0; i < 8; ++i) {
    int ci = w * 8 + i;                              // 32 rows: 0..15 h2, 16..31 Tt
    int t = ci & 15;
    const short* src = (ci < 16) ? h2 : Tt;
    short* dst = (ci < 16) ? hq : tk;
    ldscp16(src + (long)(t * 1024 + hw) * 512 + lane * 8,
            dst + t * RS + lane * 8);
  }
  const int c0 = lane * 8;
  uint4 vch[16];
#pragma unroll
  for (int tp = 0; tp < 16; ++tp)
    vch[tp] = *(const uint4*)(h2 + (long)(tp * 1024 + hw) * 512 + c0);
  __syncthreads();

  if (w == 0) {
    const int quad = lane >> 4, m = lane & 15;
    f32x4 sacc = {};
#pragma unroll
    for (int s = 0; s < 16; ++s) {
      bf16x8 aq = *(const bf16x8*)&hq[m * RS + quad * 8 + s * 32];
      bf16x8 bk = *(const bf16x8*)&tk[m * RS + quad * 8 + s * 32];
      sacc = __builtin_amdgcn_mfma_f32_16x16x32_bf16(aq, bk, sacc, 0, 0, 0);
    }
    const float rmsj = 22.627416997969522f /
                       fmaxf(sqrtf(ss[m * 1024 + hw]), 1e-12f);
    const float uj = ut[m * 1024 + hw];
#pragma unroll
    for (int r = 0; r < 4; ++r) {
      const int i = quad * 4 + r;
      const int j = m;
      const float rmsi = 22.627416997969522f /
                         fmaxf(sqrtf(ss[i * 1024 + hw]), 1e-12f);
      const bool allowed = (j <= i) && (wnd <= 0 || (i - j) < wnd);
      float val = allowed ? scale * (rmsi * rmsj * sacc[r] + rmsj * uj) : -1e30f;
      float mx = val;
#pragma unroll
      for (int off = 1; off < 16; off <<= 1) mx = fmaxf(mx, __shfl_xor(mx, off));
      float e = allowed ? __expf(val - mx) : 0.f;
      float sum = e;
#pragma unroll
      for (int off = 1; off < 16; off <<= 1) sum += __shfl_xor(sum, off);
      Plds[i][j] = (e / sum) * rmsj;                 // rms_j folded into P (V-fold)
    }
  }
  __syncthreads();

#pragma unroll
  for (int r = 0; r < 4; ++r) {
    const int t = w * 4 + r;
    const int tlo = (wnd > 0 && t - wnd + 1 > 0) ? t - wnd + 1 : 0;
    float a0 = 0.f, a1 = 0.f, a2 = 0.f, a3 = 0.f,
          a4 = 0.f, a5 = 0.f, a6 = 0.f, a7 = 0.f;
#pragma unroll
    for (int tp = 0; tp < 16; ++tp) {
      const float p = (tp >= tlo && tp <= t) ? Plds[t][tp] : 0.f;
      const uint4 vv = vch[tp];
      a0 += p * blo(vv.x); a1 += p * bhi(vv.x);
      a2 += p * blo(vv.y); a3 += p * bhi(vv.y);
      a4 += p * blo(vv.z); a5 += p * bhi(vv.z);
      a6 += p * blo(vv.w); a7 += p * bhi(vv.w);
    }
    uint4 ov;
    ov.x = packbf(a0, a1); ov.y = packbf(a2, a3);
    ov.z = packbf(a4, a5); ov.w = packbf(a6, a7);
    *(uint4*)(o + (long)(t * 1024 + hw) * 512 + c0) = ov;
  }
}

// ---------------------------------------------------------------------------
// Launch
// ---------------------------------------------------------------------------
extern "C" void kernel_launch(void* const* d_in, const int* in_sizes, int n_in,
                              void* d_out, int out_size, void* d_ws, size_t ws_size,
                              hipStream_t stream) {
  const float* x    = (const float*)d_in[0];
  const float* qs_w = (const float*)d_in[1];
  const float* qs_b = (const float*)d_in[2];
  const float* ks_w = (const float*)d_in[3];
  const float* ks_b = (const float*)d_in[4];
  const float* vs_w = (const float*)d_in[5];
  const float* vs_b = (const float*)d_in[6];
  const float* ps_w = (const float*)d_in[7];
  const float* ps_b = (const float*)d_in[8];
  const float* qt_w = (const float*)d_in[9];
  const float* qt_b = (const float*)d_in[10];
  const float* kt_w = (const float*)d_in[11];
  const float* kt_b = (const float*)d_in[12];
  const float* vt_w = (const float*)d_in[13];
  const float* vt_b = (const float*)d_in[14];
  const float* pt_w = (const float*)d_in[15];
  const float* pt_b = (const float*)d_in[16];
  const float* g_s  = (const float*)d_in[17];
  const float* g_t  = (const float*)d_in[18];
  const int*   wnd  = (const int*)d_in[19];
  float* out = (float*)d_out;
  (void)ks_b; (void)kt_b;   // K biases appear only via wu (zero cross-terms cancel)

  // workspace carve (~136 MB)
  char* w = (char*)d_ws;
  short* Wb   = (short*)(w);                               // 4 MB: 8 weight slots
  float* ss_s = (float*)(w + (4L << 20));                  // 64 KB (zeroed group start)
  float* ss_t = (float*)(w + (4L << 20) + (64 << 10));     // 64 KB
  float* rsum = (float*)(w + (4L << 20) + (128 << 10));    // 64 KB
  float* us   = (float*)(w + (4L << 20) + (192 << 10));    // 64 KB
  float* ut   = (float*)(w + (4L << 20) + (256 << 10));    // 64 KB (zeroed group end)
  float* bt_s = (float*)(w + (4L << 20) + (320 << 10));    // 2 KB folded bias
  float* bt_t = (float*)(w + (4L << 20) + (324 << 10));    // 2 KB
  float* wus  = (float*)(w + (4L << 20) + (328 << 10));    // 2 KB u-weights
  float* wut  = (float*)(w + (4L << 20) + (332 << 10));    // 2 KB
  short* WF   = (short*)(w + (4L << 20) + (512 << 10));    // 2 MB: Wpv_s|Wpv_t|Mqk_s|Mqk_t
  short* Wpv  = WF;
  short* Mqk  = WF + 2 * 262144;
  short* hb   = (short*)(w + (8L << 20));                  // 16 MB: [16384][512] bf16 x^T
  short* Tb   = (short*)(w + (24L << 20));                 // 16 MB: [16384][512] T = M.h
  short* xb   = (short*)(w + (40L << 20));                 // 16 MB: [512][16384] bf16 x
  short* oT   = (short*)(w + (56L << 20));                 // 16 MB: [16384][512] h~
  short* h2   = (short*)(w + (72L << 20));                 // 16 MB: [16384][512]
  short* S    = (short*)(w + (88L << 20));                 // 32 MB: [16][1024][1024]
  (void)in_sizes; (void)n_in; (void)out_size; (void)ws_size;

  const float scale = 0.04419417382415922f;                // 512^-0.5

  setup_all<<<9024, 256, 0, stream>>>(
      qs_w, ks_w, vs_w, ps_w, qt_w, kt_w, vt_w, pt_w, g_s, g_t, Wb, ss_s,
      qs_b, vs_b, ps_b, qt_b, vt_b, pt_b, bt_s, bt_t, wus, wut);
  // Merged weight folds: z0 Wpv_s=ps.vs_g, z1 Wpv_t=pt.vt_g,
  // z2 Mqk_s=qs_g^T.ks_g, z3 Mqk_t=qt_g^T.kt_g
  gemm_nt<short, 128, 1, 64><<<dim3(4, 4, 4), 256, 0, stream>>>(
      Wb, Wb, WF, 512, 512, 512, 512, 1.f);

  // ---------------- spatial ----------------
  txp_sumsq<<<dim3(256, 8, 1), 256, 0, stream>>>(x, hb, xb, ss_s, wus, us);
  // T[n][a] = hb[n,:] . Mqk_s[a,:]
  gemm8<short, 0, 0, 0, 0, 256, 128, 1><<<dim3(64, 4, 1), 512, 0, stream>>>(
      hb, Mqk, Tb, nullptr, nullptr, nullptr, nullptr, nullptr, nullptr,
      nullptr, 512, 512, 512, 512, 0, 0, 0, 0, 1.f);
  // expS'[t][l][m] = exp(scale*rms_m*(rms_l*(hb_l.T_m)+us_m))*rms_m ; rsum+=
  gemm8<short, 0, 4, 0, 1, 128, 256, 1><<<dim3(8, 4, 16), 512, 0, stream>>>(
      hb, Tb, S, nullptr, ss_s, us, rsum, nullptr, nullptr, nullptr,
      512, 512, 512, 1024,
      1024L * 512, 1024L * 512, 1024L * 1024, 1024, scale);
  // h~[n][c] = (1/rsum) * sum_m expS'[l,m] * xb[c,m]
  gemm8<short, 0, 3, 0, 0, 128, 256, 1><<<dim3(8, 2, 16), 512, 0, stream>>>(
      S, xb, oT, nullptr, rsum, nullptr, nullptr, nullptr, nullptr, nullptr,
      1024, 1024, 16384, 512,
      1024L * 1024, 1024L, 1024L * 512, 1024, 1.f);
  // h2[n][c] = bf16( hb[n][c] + bt_s[c] + (oT.Wpv_s^T)[n][c] );
  //   ss_t += val^2 ; ut += val*wut[c]
  gemm8<short, 2, 0, 2, 3, 256, 128, 1><<<dim3(64, 4, 1), 512, 0, stream>>>(
      oT, Wpv, h2, bt_s, nullptr, nullptr, ss_t, ut, wut, hb,
      512, 512, 512, 512, 0, 0, 0, 1024, 1.f);

  // ---------------- temporal ----------------
  // Tt[n][a] = h2[n,:] . Mqk_t[a,:]
  gemm8<short, 0, 0, 0, 0, 256, 128, 1><<<dim3(64, 4, 1), 512, 0, stream>>>(
      h2, Mqk + 262144, Tb, nullptr, nullptr, nullptr, nullptr, nullptr,
      nullptr, nullptr, 512, 512, 512, 512, 0, 0, 0, 0, 1.f);
  temporal_attn_v5<<<1024, 256, 0, stream>>>(h2, Tb, ss_t, ut, wnd, oT, scale);
  // out[c,n] = h2[n][c] + bt_t[c] + Wpv_t[c,:] . h~[n,:]   (fp32, c-major)
  gemm8<float, 1, 0, 3, 0, 128, 256, 1><<<dim3(4, 64, 1), 512, 0, stream>>>(
      Wpv + 262144, oT, out, bt_t, nullptr, nullptr, nullptr, nullptr,
      nullptr, h2, 512, 512, 512, 16384, 0, 0, 0, 0, 1.f);
}

// Round 10
// 317.435 us; speedup vs baseline: 1.0419x; 1.0419x over previous
//
#include <hip/hip_runtime.h>

// ---------------------------------------------------------------------------
// Types & helpers
// ---------------------------------------------------------------------------
typedef __attribute__((ext_vector_type(8))) short bf16x8;
typedef __attribute__((ext_vector_type(4))) float f32x4;

__device__ __forceinline__ short f2bf(float f) {
  union { float f; unsigned u; } a; a.f = f;
  unsigned r = a.u + 0x7fffu + ((a.u >> 16) & 1u);   // RNE
  return (short)(r >> 16);
}
__device__ __forceinline__ float bf2f(short s) {
  union { unsigned u; float f; } a;
  a.u = ((unsigned)(unsigned short)s) << 16; return a.f;
}
__device__ __forceinline__ float blo(unsigned u) { union { unsigned u; float f; } a; a.u = u << 16; return a.f; }
__device__ __forceinline__ float bhi(unsigned u) { union { unsigned u; float f; } a; a.u = u & 0xffff0000u; return a.f; }
__device__ __forceinline__ unsigned packbf(float lo, float hi) {
  return (unsigned)(unsigned short)f2bf(lo) | ((unsigned)(unsigned short)f2bf(hi) << 16);
}
__device__ __forceinline__ void ldscp16(const void* g, void* l) {
  __builtin_amdgcn_global_load_lds((const __attribute__((address_space(1))) void*)g,
                                   (__attribute__((address_space(3))) void*)l, 16, 0, 0);
}
__device__ __forceinline__ void stv(float* p, float v) { *p = v; }
__device__ __forceinline__ void stv(short* p, float v) { *p = f2bf(v); }

// ---------------------------------------------------------------------------
// Merged setup (unchanged).
// ---------------------------------------------------------------------------
__global__ __launch_bounds__(256) void setup_all(
    const float* __restrict__ w0, const float* __restrict__ w1,
    const float* __restrict__ w2, const float* __restrict__ w3,
    const float* __restrict__ w4, const float* __restrict__ w5,
    const float* __restrict__ w6, const float* __restrict__ w7,
    const float* __restrict__ g_s, const float* __restrict__ g_t,
    short* __restrict__ Wb, float* __restrict__ zs,
    const float* __restrict__ qs_b, const float* __restrict__ vs_b,
    const float* __restrict__ ps_b, const float* __restrict__ qt_b,
    const float* __restrict__ vt_b, const float* __restrict__ pt_b,
    float* __restrict__ bt_s, float* __restrict__ bt_t,
    float* __restrict__ wus, float* __restrict__ wut) {
  const int bid = blockIdx.x, tid = threadIdx.x;
  if (bid < 8192) {                                  // ---- cvt_w ----
    int idx = bid * 256 + tid;
    const float* ws[8] = {w0, w1, w2, w3, w4, w5, w6, w7};
    int wi = idx >> 18, loc = idx & 262143;
    int r = loc >> 9, q = loc & 511;
    float v, g;
    if (wi == 3 || wi == 7) { v = ws[wi][loc]; g = 1.f; }
    else {                                           // transposed, gamma on c_in=r
      v = ws[wi][q * 512 + r];
      g = (wi <= 2) ? g_s[r] : g_t[r];
    }
    Wb[idx] = f2bf(v * g);
  } else if (bid < 8512) {                           // ---- zero 320 KB ----
    zs[(bid - 8192) * 256 + tid] = 0.f;
  } else {                                           // ---- row folds ----
    const int w = tid >> 6, lane = tid & 63;
    const int b = (bid - 8512) * 4 + w;              // [0,2048)
    float s = 0.f;
    if (b < 1024) {                                  // bt = p_w.v_b + p_b
      const bool sp = b < 512;
      const float* W = sp ? w3 : w7;                 // ps_w : pt_w
      const float* vb = sp ? vs_b : vt_b;
      const int r = b & 511;
#pragma unroll
      for (int c = lane; c < 512; c += 64) s += W[r * 512 + c] * vb[c];
#pragma unroll
      for (int off = 32; off > 0; off >>= 1) s += __shfl_xor(s, off);
      if (lane == 0) (sp ? bt_s : bt_t)[r] = s + (sp ? ps_b : pt_b)[r];
    } else {                                         // wu = g * K_w^T.q_b
      const bool sp = b < 1536;
      const float* W = sp ? w1 : w5;                 // ks_w : kt_w
      const float* qb = sp ? qs_b : qt_b;
      const int c = b & 511;
#pragma unroll
      for (int o = lane; o < 512; o += 64) s += W[o * 512 + c] * qb[o];
#pragma unroll
      for (int off = 32; off > 0; off >>= 1) s += __shfl_xor(s, off);
      if (lane == 0)
        (sp ? wus : wut)[c] = s * (sp ? g_s[c] : g_t[c]);
    }
  }
}

// ---------------------------------------------------------------------------
// Transpose + sum-of-squares + u-dot (unchanged).
// ---------------------------------------------------------------------------
__global__ __launch_bounds__(256) void txp_sumsq(
    const float* __restrict__ src, short* __restrict__ dst,
    short* __restrict__ xb, float* __restrict__ ss,
    const float* __restrict__ wu, float* __restrict__ us) {
  constexpr long N = 16384;
  __shared__ short T[64][66];
  __shared__ float part[16][16][4];
  __shared__ float part2[16][16][4];
  const int tid = threadIdx.x;
  const long n0 = (long)blockIdx.x * 64;
  const int c0 = blockIdx.y * 64;
  const int n4 = (tid & 15) * 4;
  float s0 = 0.f, s1 = 0.f, s2 = 0.f, s3 = 0.f;
  float u0 = 0.f, u1 = 0.f, u2 = 0.f, u3 = 0.f;
#pragma unroll
  for (int i = 0; i < 4; ++i) {
    int cl = i * 16 + (tid >> 4);
    float4 v = *(const float4*)&src[(long)(c0 + cl) * N + n0 + n4];
    float wc = wu[c0 + cl];
    s0 += v.x * v.x; s1 += v.y * v.y; s2 += v.z * v.z; s3 += v.w * v.w;
    u0 += wc * v.x; u1 += wc * v.y; u2 += wc * v.z; u3 += wc * v.w;
    short e0 = f2bf(v.x), e1 = f2bf(v.y), e2 = f2bf(v.z), e3 = f2bf(v.w);
    T[n4 + 0][cl] = e0; T[n4 + 1][cl] = e1;
    T[n4 + 2][cl] = e2; T[n4 + 3][cl] = e3;
    uint2 o;
    o.x = (unsigned)(unsigned short)e0 | ((unsigned)(unsigned short)e1 << 16);
    o.y = (unsigned)(unsigned short)e2 | ((unsigned)(unsigned short)e3 << 16);
    *(uint2*)&xb[(long)(c0 + cl) * N + n0 + n4] = o;
  }
  part[tid >> 4][tid & 15][0] = s0; part[tid >> 4][tid & 15][1] = s1;
  part[tid >> 4][tid & 15][2] = s2; part[tid >> 4][tid & 15][3] = s3;
  part2[tid >> 4][tid & 15][0] = u0; part2[tid >> 4][tid & 15][1] = u1;
  part2[tid >> 4][tid & 15][2] = u2; part2[tid >> 4][tid & 15][3] = u3;
  __syncthreads();
  if (tid < 64) {
    float s = 0.f, u = 0.f;
#pragma unroll
    for (int cg = 0; cg < 16; ++cg) {
      s += part[cg][tid >> 2][tid & 3];
      u += part2[cg][tid >> 2][tid & 3];
    }
    atomicAdd(&ss[n0 + tid], s);
    atomicAdd(&us[n0 + tid], u);
  }
#pragma unroll
  for (int p = 0; p < 4; ++p) {
    int nl = p * 16 + (tid >> 4);
    int cl = (tid & 15) * 4;
    uint2 o;
    o.x = (unsigned)(unsigned short)T[nl][cl] |
          ((unsigned)(unsigned short)T[nl][cl + 1] << 16);
    o.y = (unsigned)(unsigned short)T[nl][cl + 2] |
          ((unsigned)(unsigned short)T[nl][cl + 3] << 16);
    *(uint2*)&dst[(n0 + nl) * 512 + c0 + cl] = o;
  }
}

// ---------------------------------------------------------------------------
// Generic NT GEMM — r4 best-measured config (kept for fold + S + PV):
// BM=128, BK=64, single-buffer 2-barrier loop, 32 KB LDS, (256,4),
// bijective XCD chunk swizzle (SWZ).
// ---------------------------------------------------------------------------
template <typename OutT, int BIAS_MODE, int SCALE_MODE, int RESID_MODE, int EPI,
          int BM = 128, int FOLD = 0, int BK = 64, int SWZ = 0>
__global__ __launch_bounds__(256, 4) void gemm_nt(
    const short* __restrict__ A, const short* __restrict__ B,
    OutT* __restrict__ D, const float* __restrict__ bias,
    const float* __restrict__ ssv, const float* __restrict__ uvec,
    float* __restrict__ rs, float* __restrict__ rs2,
    const float* __restrict__ wvec,
    const float* __restrict__ residf, const short* __restrict__ residb,
    int K, int lda, int ldb, int ldd,
    long aBatch, long bBatch, long dBatch, long sBatch, float scale) {
  constexpr int WR = BM / 64;                        // wave rows
  constexpr int WC = 4 / WR;                         // wave cols
  constexpr int NW = (128 / WC) / 16;                // B-frags per wave
  constexpr int CH = BK / 8;                         // 16B chunks per row
  constexpr int MSK = CH - 1;
  constexpr int RPR = 256 / CH;                      // rows staged per round
  __shared__ short As[BM * BK];
  __shared__ short Bs[128 * BK];
  const int tid = threadIdx.x;

  int lin = blockIdx.x + gridDim.x * (blockIdx.y + gridDim.y * blockIdx.z);
  if (SWZ) {
    const int nwg = gridDim.x * gridDim.y * gridDim.z;
    const int q = nwg >> 3, r = nwg & 7;
    const int xcd = lin & 7, idx = lin >> 3;
    lin = (xcd < r ? xcd * (q + 1) : r * (q + 1) + (xcd - r) * q) + idx;
  }
  const int bx = lin % gridDim.x;
  const int t1 = lin / gridDim.x;
  const int by = t1 % gridDim.y;
  const int bz = t1 / gridDim.y;

  const long i0 = (long)bx * BM;
  const long j0 = (long)by * 128;
  long aOff, bOff;
  if (FOLD) {
    aOff = 262144L * (bz < 2 ? 3 + 4 * bz : 4 * (bz - 2));
    bOff = 262144L * (bz < 2 ? 2 + 4 * bz : 1 + 4 * (bz - 2));
  } else {
    aOff = bz * aBatch; bOff = bz * bBatch;
  }
  const short* Ab = A + aOff + i0 * lda;
  const short* Bb = B + bOff + j0 * ldb;
  const int srow = tid / CH, scol = tid & MSK;
  const int lane = tid & 63;
  const int waveid = tid >> 6;
  const int wr = (waveid / WC) * 64;
  const int wc = (waveid % WC) * 64;
  const int quad = lane >> 4, l15 = lane & 15;

  f32x4 acc[4][NW] = {};

  for (int k0 = 0; k0 < K; k0 += BK) {
    __syncthreads();
#pragma unroll
    for (int p = 0; p < BM / RPR; ++p) {
      int row = p * RPR + srow;
      int gc = (scol ^ (row & MSK)) << 3;
      ldscp16(Ab + (long)row * lda + k0 + gc, &As[p * 2048 + tid * 8]);
    }
#pragma unroll
    for (int p = 0; p < 128 / RPR; ++p) {
      int row = p * RPR + srow;
      int gc = (scol ^ (row & MSK)) << 3;
      ldscp16(Bb + (long)row * ldb + k0 + gc, &Bs[p * 2048 + tid * 8]);
    }
    __syncthreads();
#pragma unroll
    for (int kk = 0; kk < BK / 32; ++kk) {
      bf16x8 af[4], bfr[NW];
#pragma unroll
      for (int a = 0; a < 4; ++a) {
        int row = wr + a * 16 + l15;
        int g = kk * 4 + quad;
        af[a] = *(const bf16x8*)&As[row * BK + ((g ^ (row & MSK)) << 3)];
      }
#pragma unroll
      for (int b = 0; b < NW; ++b) {
        int row = wc + b * 16 + l15;
        int g = kk * 4 + quad;
        bfr[b] = *(const bf16x8*)&Bs[row * BK + ((g ^ (row & MSK)) << 3)];
      }
#pragma unroll
      for (int a = 0; a < 4; ++a)
#pragma unroll
        for (int b = 0; b < NW; ++b)
          acc[a][b] = __builtin_amdgcn_mfma_f32_16x16x32_bf16(af[a], bfr[b], acc[a][b], 0, 0, 0);
    }
  }

  const long Doff = bz * dBatch;
#pragma unroll
  for (int a = 0; a < 4; ++a) {
    const int rb = (int)i0 + wr + a * 16 + quad * 4;   // C/D: row = quad*4+reg
    float rsc[4];
    if (SCALE_MODE == 1 || SCALE_MODE == 4) {
#pragma unroll
      for (int r = 0; r < 4; ++r)
        rsc[r] = 22.627416997969522f /
                 fmaxf(sqrtf(ssv[bz * sBatch + rb + r]), 1e-12f);
    }
    if (SCALE_MODE == 3) {
#pragma unroll
      for (int r = 0; r < 4; ++r)
        rsc[r] = 1.f / ssv[bz * sBatch + rb + r];
    }
    float rp1[4] = {0.f, 0.f, 0.f, 0.f};
    float rp2[4] = {0.f, 0.f, 0.f, 0.f};
#pragma unroll
    for (int b = 0; b < NW; ++b) {
      const int cc = (int)j0 + wc + b * 16 + l15;      // C/D: col = lane&15
      float csc = 1.f, uu = 0.f, wv = 0.f;
      if (SCALE_MODE == 2 || SCALE_MODE == 4)
        csc = 22.627416997969522f /
              fmaxf(sqrtf(ssv[bz * sBatch + cc]), 1e-12f);
      if (SCALE_MODE == 4) uu = uvec[bz * sBatch + cc];
      if (EPI == 3) wv = wvec[cc];
      uint2 rtv;
      if (RESID_MODE == 3)
        rtv = *(const uint2*)&residb[(long)cc * 512 + rb];
#pragma unroll
      for (int r = 0; r < 4; ++r) {
        float val;
        if (SCALE_MODE == 4) {
          val = __expf(scale * csc * (rsc[r] * acc[a][b][r] + uu));
          rp1[r] += val;
          val *= csc;
        } else {
          val = acc[a][b][r] * scale;
          if (SCALE_MODE == 1 || SCALE_MODE == 3) val *= rsc[r];
          if (SCALE_MODE == 2) val *= csc;
        }
        if (BIAS_MODE == 1) val += bias[rb + r];
        if (BIAS_MODE == 2) val += bias[cc];
        const long off = Doff + (long)(rb + r) * ldd + cc;
        if (RESID_MODE == 1) val += residf[off];
        if (RESID_MODE == 2) val += bf2f(residb[off]);
        if (RESID_MODE == 3) val += bf2f(((const short*)&rtv)[r]);
        stv(D + off, val);
        if (EPI == 3) { rp1[r] += val * val; rp2[r] += val * wv; }
      }
    }
    if (EPI == 1 || EPI == 3) {
#pragma unroll
      for (int r = 0; r < 4; ++r) {
        float s = rp1[r];
#pragma unroll
        for (int off = 1; off < 16; off <<= 1) s += __shfl_xor(s, off);
        if (l15 == 0) atomicAdd(&rs[bz * sBatch + rb + r], s);
      }
      if (EPI == 3) {
#pragma unroll
        for (int r = 0; r < 4; ++r) {
          float s = rp2[r];
#pragma unroll
          for (int off = 1; off < 16; off <<= 1) s += __shfl_xor(s, off);
          if (l15 == 0) atomicAdd(&rs2[bz * sBatch + rb + r], s);
        }
      }
    }
  }
}

// ---------------------------------------------------------------------------
// gemm_ws — weight-stationary, barrier-free streamed GEMM for the four
// 16384x512x512 GEMMs. The 0.5 MB stationary operand's 64-row panel (whole
// K=512) is staged to LDS ONCE (one barrier); then a register-streamed loop:
// stream fragments read straight from global (16 rows x 64B = 1KB/instr,
// sector-perfect), panel fragments from LDS, 16 MFMA per kk, kk=0..15 fully
// unrolled, NO barriers -> waves drift and self-hide latency (m114); the
// r0-r8 invariant was that every barrier-staged structure pins MfmaUtil at
// ~9-14% at these K=512 shapes.
// STREAM_A=1: stream feeds A-frags (D rows = stream) — Tb, h2, Tt.
// STREAM_A=0: stream feeds B-frags (D rows = panel)  — out (D[c][n]).
// Grid dim3(8,64): x = panel idx (fastest) so the chunked XCD swizzle puts
// consecutive tiles (same stream-chunk, all 8 panels) on one XCD: each
// stream row is HBM-fetched once per XCD and L2-served for the rest.
// LDS 64 KB -> 2 blocks/CU.
// ---------------------------------------------------------------------------
template <typename OutT, int BIAS_MODE, int RESID_MODE, int EPI, int STREAM_A>
__global__ __launch_bounds__(256, 2) void gemm_ws(
    const short* __restrict__ Sm,                    // stationary [512][512]
    const short* __restrict__ St,                    // stream [16384][512]
    OutT* __restrict__ D, const float* __restrict__ bias,
    float* __restrict__ rs, float* __restrict__ rs2,
    const float* __restrict__ wvec, const short* __restrict__ residb,
    int ldd) {
  __shared__ short Ps[64 * 512];                     // 64 KB panel
  const int tid = threadIdx.x;
  const int lane = tid & 63, w = tid >> 6;
  const int quad = lane >> 4, l15 = lane & 15;

  int lin = blockIdx.x + (blockIdx.y << 3);          // 512 blocks, x=panel
  { int idx = lin >> 3, xcd = lin & 7; lin = xcd * 64 + idx; }  // XCD chunks
  const int bx = lin & 7, by = lin >> 3;
  const int p0 = bx * 64;                            // panel rows
  const long s0 = (long)by * 256;                    // stream rows

  // stage panel rows p0..p0+63, whole K; xor-swizzled chunks (c ^ (r&7))
#pragma unroll
  for (int i = 0; i < 16; ++i) {
    int idx = i * 256 + tid;
    int r = idx >> 6, c = idx & 63;
    ldscp16(Sm + (p0 + r) * 512 + ((c ^ (r & 7)) << 3), &Ps[idx * 8]);
  }
  __syncthreads();                                   // the ONLY barrier

  const long sbase = s0 + w * 64;                    // this wave's stream rows
  f32x4 acc[4][4] = {};
#pragma unroll
  for (int kk = 0; kk < 16; ++kk) {
    bf16x8 gf[4], lf[4];
#pragma unroll
    for (int a = 0; a < 4; ++a)
      gf[a] = *(const bf16x8*)&St[(sbase + a * 16 + l15) * 512 + kk * 32 + quad * 8];
#pragma unroll
    for (int b = 0; b < 4; ++b) {
      int pr = b * 16 + l15;
      lf[b] = *(const bf16x8*)&Ps[pr * 512 + (((kk * 4 + quad) ^ (pr & 7)) << 3)];
    }
#pragma unroll
    for (int a = 0; a < 4; ++a)
#pragma unroll
      for (int b = 0; b < 4; ++b)
        acc[a][b] = __builtin_amdgcn_mfma_f32_16x16x32_bf16(
            STREAM_A ? gf[a] : lf[a], STREAM_A ? lf[b] : gf[b], acc[a][b], 0, 0, 0);
  }

  const int rbase = STREAM_A ? (int)sbase : p0;      // D rows
  const int cbase = STREAM_A ? p0 : (int)sbase;      // D cols
#pragma unroll
  for (int a = 0; a < 4; ++a) {
    const int rb = rbase + a * 16 + quad * 4;        // C/D: row = quad*4+reg
    float rp1[4] = {0.f, 0.f, 0.f, 0.f};
    float rp2[4] = {0.f, 0.f, 0.f, 0.f};
#pragma unroll
    for (int b = 0; b < 4; ++b) {
      const int cc = cbase + b * 16 + l15;           // C/D: col = lane&15
      float wv = 0.f;
      if (EPI == 3) wv = wvec[cc];
      uint2 rtv;
      if (RESID_MODE == 3)
        rtv = *(const uint2*)&residb[(long)cc * 512 + rb];
#pragma unroll
      for (int r = 0; r < 4; ++r) {
        float val = acc[a][b][r];
        if (BIAS_MODE == 1) val += bias[rb + r];
        if (BIAS_MODE == 2) val += bias[cc];
        const long off = (long)(rb + r) * ldd + cc;
        if (RESID_MODE == 2) val += bf2f(residb[off]);
        if (RESID_MODE == 3) val += bf2f(((const short*)&rtv)[r]);
        stv(D + off, val);
        if (EPI == 3) { rp1[r] += val * val; rp2[r] += val * wv; }
      }
    }
    if (EPI == 3) {
#pragma unroll
      for (int r = 0; r < 4; ++r) {
        float s = rp1[r];
#pragma unroll
        for (int off = 1; off < 16; off <<= 1) s += __shfl_xor(s, off);
        if (l15 == 0) atomicAdd(&rs[rb + r], s);
      }
#pragma unroll
      for (int r = 0; r < 4; ++r) {
        float s = rp2[r];
#pragma unroll
        for (int off = 1; off < 16; off <<= 1) s += __shfl_xor(s, off);
        if (l15 == 0) atomicAdd(&rs2[rb + r], s);
      }
    }
  }
}

// ---------------------------------------------------------------------------
// Temporal attention v5 (unchanged).
// ---------------------------------------------------------------------------
__global__ __launch_bounds__(256) void temporal_attn_v5(
    const short* __restrict__ h2, const short* __restrict__ Tt,
    const float* __restrict__ ss, const float* __restrict__ ut,
    const int* __restrict__ wndp, short* __restrict__ o, float scale) {
  constexpr int RS = 520;                            // 512 + 8 pad
  __shared__ short hq[16 * RS];
  __shared__ short tk[16 * RS];
  __shared__ float Plds[16][17];
  const int tid = threadIdx.x;
  const int w = tid >> 6, lane = tid & 63;
  const int hw = blockIdx.x;
  const int wnd = *wndp;

#pragma unroll
  for (int i = 0; i < 8; ++i) {
    int ci = w * 8 + i;                              // 32 rows: 0..15 h2, 16..31 Tt
    int t = ci & 15;
    const short* src = (ci < 16) ? h2 : Tt;
    short* dst = (ci < 16) ? hq : tk;
    ldscp16(src + (long)(t * 1024 + hw) * 512 + lane * 8,
            dst + t * RS + lane * 8);
  }
  const int c0 = lane * 8;
  uint4 vch[16];
#pragma unroll
  for (int tp = 0; tp < 16; ++tp)
    vch[tp] = *(const uint4*)(h2 + (long)(tp * 1024 + hw) * 512 + c0);
  __syncthreads();

  if (w == 0) {
    const int quad = lane >> 4, m = lane & 15;
    f32x4 sacc = {};
#pragma unroll
    for (int s = 0; s < 16; ++s) {
      bf16x8 aq = *(const bf16x8*)&hq[m * RS + quad * 8 + s * 32];
      bf16x8 bk = *(const bf16x8*)&tk[m * RS + quad * 8 + s * 32];
      sacc = __builtin_amdgcn_mfma_f32_16x16x32_bf16(aq, bk, sacc, 0, 0, 0);
    }
    const float rmsj = 22.627416997969522f /
                       fmaxf(sqrtf(ss[m * 1024 + hw]), 1e-12f);
    const float uj = ut[m * 1024 + hw];
#pragma unroll
    for (int r = 0; r < 4; ++r) {
      const int i = quad * 4 + r;
      const int j = m;
      const float rmsi = 22.627416997969522f /
                         fmaxf(sqrtf(ss[i * 1024 + hw]), 1e-12f);
      const bool allowed = (j <= i) && (wnd <= 0 || (i - j) < wnd);
      float val = allowed ? scale * (rmsi * rmsj * sacc[r] + rmsj * uj) : -1e30f;
      float mx = val;
#pragma unroll
      for (int off = 1; off < 16; off <<= 1) mx = fmaxf(mx, __shfl_xor(mx, off));
      float e = allowed ? __expf(val - mx) : 0.f;
      float sum = e;
#pragma unroll
      for (int off = 1; off < 16; off <<= 1) sum += __shfl_xor(sum, off);
      Plds[i][j] = (e / sum) * rmsj;                 // rms_j folded into P (V-fold)
    }
  }
  __syncthreads();

#pragma unroll
  for (int r = 0; r < 4; ++r) {
    const int t = w * 4 + r;
    const int tlo = (wnd > 0 && t - wnd + 1 > 0) ? t - wnd + 1 : 0;
    float a0 = 0.f, a1 = 0.f, a2 = 0.f, a3 = 0.f,
          a4 = 0.f, a5 = 0.f, a6 = 0.f, a7 = 0.f;
#pragma unroll
    for (int tp = 0; tp < 16; ++tp) {
      const float p = (tp >= tlo && tp <= t) ? Plds[t][tp] : 0.f;
      const uint4 vv = vch[tp];
      a0 += p * blo(vv.x); a1 += p * bhi(vv.x);
      a2 += p * blo(vv.y); a3 += p * bhi(vv.y);
      a4 += p * blo(vv.z); a5 += p * bhi(vv.z);
      a6 += p * blo(vv.w); a7 += p * bhi(vv.w);
    }
    uint4 ov;
    ov.x = packbf(a0, a1); ov.y = packbf(a2, a3);
    ov.z = packbf(a4, a5); ov.w = packbf(a6, a7);
    *(uint4*)(o + (long)(t * 1024 + hw) * 512 + c0) = ov;
  }
}

// ---------------------------------------------------------------------------
// Launch
// ---------------------------------------------------------------------------
extern "C" void kernel_launch(void* const* d_in, const int* in_sizes, int n_in,
                              void* d_out, int out_size, void* d_ws, size_t ws_size,
                              hipStream_t stream) {
  const float* x    = (const float*)d_in[0];
  const float* qs_w = (const float*)d_in[1];
  const float* qs_b = (const float*)d_in[2];
  const float* ks_w = (const float*)d_in[3];
  const float* ks_b = (const float*)d_in[4];
  const float* vs_w = (const float*)d_in[5];
  const float* vs_b = (const float*)d_in[6];
  const float* ps_w = (const float*)d_in[7];
  const float* ps_b = (const float*)d_in[8];
  const float* qt_w = (const float*)d_in[9];
  const float* qt_b = (const float*)d_in[10];
  const float* kt_w = (const float*)d_in[11];
  const float* kt_b = (const float*)d_in[12];
  const float* vt_w = (const float*)d_in[13];
  const float* vt_b = (const float*)d_in[14];
  const float* pt_w = (const float*)d_in[15];
  const float* pt_b = (const float*)d_in[16];
  const float* g_s  = (const float*)d_in[17];
  const float* g_t  = (const float*)d_in[18];
  const int*   wnd  = (const int*)d_in[19];
  float* out = (float*)d_out;
  (void)ks_b; (void)kt_b;   // K biases appear only via wu (zero cross-terms cancel)

  // workspace carve (~136 MB)
  char* w = (char*)d_ws;
  short* Wb   = (short*)(w);                               // 4 MB: 8 weight slots
  float* ss_s = (float*)(w + (4L << 20));                  // 64 KB (zeroed group start)
  float* ss_t = (float*)(w + (4L << 20) + (64 << 10));     // 64 KB
  float* rsum = (float*)(w + (4L << 20) + (128 << 10));    // 64 KB
  float* us   = (float*)(w + (4L << 20) + (192 << 10));    // 64 KB
  float* ut   = (float*)(w + (4L << 20) + (256 << 10));    // 64 KB (zeroed group end)
  float* bt_s = (float*)(w + (4L << 20) + (320 << 10));    // 2 KB folded bias
  float* bt_t = (float*)(w + (4L << 20) + (324 << 10));    // 2 KB
  float* wus  = (float*)(w + (4L << 20) + (328 << 10));    // 2 KB u-weights
  float* wut  = (float*)(w + (4L << 20) + (332 << 10));    // 2 KB
  short* WF   = (short*)(w + (4L << 20) + (512 << 10));    // 2 MB: Wpv_s|Wpv_t|Mqk_s|Mqk_t
  short* Wpv  = WF;
  short* Mqk  = WF + 2 * 262144;
  short* hb   = (short*)(w + (8L << 20));                  // 16 MB: [16384][512] bf16 x^T
  short* Tb   = (short*)(w + (24L << 20));                 // 16 MB: [16384][512] T = M.h
  short* xb   = (short*)(w + (40L << 20));                 // 16 MB: [512][16384] bf16 x
  short* oT   = (short*)(w + (56L << 20));                 // 16 MB: [16384][512] h~
  short* h2   = (short*)(w + (72L << 20));                 // 16 MB: [16384][512]
  short* S    = (short*)(w + (88L << 20));                 // 32 MB: [16][1024][1024]
  (void)in_sizes; (void)n_in; (void)out_size; (void)ws_size;

  const float scale = 0.04419417382415922f;                // 512^-0.5

  setup_all<<<9024, 256, 0, stream>>>(
      qs_w, ks_w, vs_w, ps_w, qt_w, kt_w, vt_w, pt_w, g_s, g_t, Wb, ss_s,
      qs_b, vs_b, ps_b, qt_b, vt_b, pt_b, bt_s, bt_t, wus, wut);
  // Merged weight folds: z0 Wpv_s=ps.vs_g, z1 Wpv_t=pt.vt_g,
  // z2 Mqk_s=qs_g^T.ks_g, z3 Mqk_t=qt_g^T.kt_g
  gemm_nt<short, 0, 0, 0, 0, 128, 1, 64, 0><<<dim3(4, 4, 4), 256, 0, stream>>>(
      Wb, Wb, WF, nullptr, nullptr, nullptr, nullptr, nullptr, nullptr,
      nullptr, nullptr, 512, 512, 512, 512, 0, 0, 262144L, 0, 1.f);

  // ---------------- spatial ----------------
  txp_sumsq<<<dim3(256, 8, 1), 256, 0, stream>>>(x, hb, xb, ss_s, wus, us);
  // T[n][a] = hb[n,:] . Mqk_s[a,:]   (weight-stationary, barrier-free)
  gemm_ws<short, 0, 0, 0, 1><<<dim3(8, 64), 256, 0, stream>>>(
      Mqk, hb, Tb, nullptr, nullptr, nullptr, nullptr, nullptr, 512);
  // expS'[t][l][m] = exp(scale*rms_m*(rms_l*(hb_l.T_m)+us_m))*rms_m ; rsum+=
  gemm_nt<short, 0, 4, 0, 1, 128, 0, 64, 1><<<dim3(8, 8, 16), 256, 0, stream>>>(
      hb, Tb, S, nullptr, ss_s, us, rsum, nullptr, nullptr, nullptr, nullptr,
      512, 512, 512, 1024,
      1024L * 512, 1024L * 512, 1024L * 1024, 1024, scale);
  // h~[n][c] = (1/rsum) * sum_m expS'[l,m] * xb[c,m]
  gemm_nt<short, 0, 3, 0, 0, 128, 0, 64, 1><<<dim3(8, 4, 16), 256, 0, stream>>>(
      S, xb, oT, nullptr, rsum, nullptr, nullptr, nullptr, nullptr,
      nullptr, nullptr, 1024, 1024, 16384, 512,
      1024L * 1024, 1024L, 1024L * 512, 1024, 1.f);
  // h2[n][c] = bf16( hb[n][c] + bt_s[c] + (oT.Wpv_s^T)[n][c] );
  //   ss_t += val^2 ; ut += val*wut[c]   (weight-stationary)
  gemm_ws<short, 2, 2, 3, 1><<<dim3(8, 64), 256, 0, stream>>>(
      Wpv, oT, h2, bt_s, ss_t, ut, wut, hb, 512);

  // ---------------- temporal ----------------
  // Tt[n][a] = h2[n,:] . Mqk_t[a,:]   (weight-stationary)
  gemm_ws<short, 0, 0, 0, 1><<<dim3(8, 64), 256, 0, stream>>>(
      Mqk + 262144, h2, Tb, nullptr, nullptr, nullptr, nullptr, nullptr, 512);
  temporal_attn_v5<<<1024, 256, 0, stream>>>(h2, Tb, ss_t, ut, wnd, oT, scale);
  // out[c,n] = h2[n][c] + bt_t[c] + Wpv_t[c,:] . h~[n,:]   (fp32, c-major;
  // weight-stationary with D rows = panel)
  gemm_ws<float, 1, 3, 0, 0><<<dim3(8, 64), 256, 0, stream>>>(
      Wpv + 262144, oT, out, bt_t, nullptr, nullptr, nullptr, h2, 16384);
}